// Round 8
// baseline (157.201 us; speedup 1.0000x reference)
//
#include <hip/hip_runtime.h>
#include <hip/hip_bf16.h>

// Problem constants (fixed by setup_inputs)
#define BB 2
#define TT 2048
#define DD 1024
#define HH 16
#define HD 64
#define WIN 16
#define NG 128          // T / stride global tokens
#define QKVLD 3072      // 3*D row stride of qkv
#define QB 128          // attn queries per block (v8)

typedef __bf16 bf16x8 __attribute__((ext_vector_type(8)));
typedef _Float16 f16x8 __attribute__((ext_vector_type(8)));
typedef float f32x4 __attribute__((ext_vector_type(4)));
typedef _Float16 h2 __attribute__((ext_vector_type(2)));
typedef __fp16 pk2_t __attribute__((ext_vector_type(2)));   // cvt_pkrtz return type

__device__ __forceinline__ unsigned short f2bf(float f) {
    union { float f; unsigned int i; } x; x.f = f;
    unsigned int r = x.i + 0x7FFFu + ((x.i >> 16) & 1u);
    return (unsigned short)(r >> 16);
}
__device__ __forceinline__ unsigned short f2h(float f) {
    union { _Float16 h; unsigned short u; } x; x.h = (_Float16)f; return x.u;
}
// pack two f32 -> f16x2 dword (v_cvt_pkrtz_f16_f32)
__device__ __forceinline__ unsigned int pk2h(float lo, float hi) {
    union { pk2_t h; unsigned int u; } X;
    X.h = __builtin_amdgcn_cvt_pkrtz(lo, hi);
    return X.u;
}

// async global->LDS, 16 B per lane; LDS dest = wave-uniform base + lane*16
__device__ __forceinline__ void gll16(const unsigned short* g, unsigned short* l) {
    __builtin_amdgcn_global_load_lds(
        (const __attribute__((address_space(1))) void*)g,
        (__attribute__((address_space(3))) void*)l,
        16, 0, 0);
}

// ---------------- fused pre-pass (one dispatch, role per block) ----------
//   blocks [0, 2048)     : x fp32 -> xb bf16 (8 elems/thread)
//   blocks [2048, 2816)  : w_qkv (1024x3072) -> wqkvT (3072x1024) bf16, 64x64 tiles
//   blocks [2816, 3072)  : w_proj (1024x1024) -> wprojT (1024x1024) bf16, 64x64 tiles
__global__ __launch_bounds__(256) void prepass_kernel(
    const float* __restrict__ x,
    const float* __restrict__ w_qkv,
    const float* __restrict__ w_proj,
    unsigned short* __restrict__ xb,
    unsigned short* __restrict__ wqkvT,
    unsigned short* __restrict__ wprojT)
{
    __shared__ float tile[64][65];
    const int bid = blockIdx.x;
    const int tid = threadIdx.x;

    if (bid < 2048) {
        const size_t i = ((size_t)bid * 256 + tid) * 8;
        float4 f0 = *(const float4*)(x + i);
        float4 f1 = *(const float4*)(x + i + 4);
        ushort4 a = { f2bf(f0.x), f2bf(f0.y), f2bf(f0.z), f2bf(f0.w) };
        ushort4 b = { f2bf(f1.x), f2bf(f1.y), f2bf(f1.z), f2bf(f1.w) };
        *(ushort4*)(xb + i) = a;
        *(ushort4*)(xb + i + 4) = b;
        return;
    }

    const float* w;
    unsigned short* wT;
    int nblk, kblk, N;
    if (bid < 2816) {
        const int b2 = bid - 2048;
        w = w_qkv; wT = wqkvT; N = 3072;
        nblk = b2 % 48; kblk = b2 / 48;
    } else {
        const int b2 = bid - 2816;
        w = w_proj; wT = wprojT; N = 1024;
        nblk = b2 % 16; kblk = b2 / 16;
    }
    const int K = 1024;
    const int n0 = nblk * 64, k0 = kblk * 64;

    // read: 64(k) x 64(n) fp32, coalesced 16 floats per thread
    {
        const int krow = tid >> 2;             // 0..63
        const int nc0  = (tid & 3) * 16;       // 0,16,32,48
        const float* src = w + (size_t)(k0 + krow) * N + n0 + nc0;
        float4 f0 = *(const float4*)(src);
        float4 f1 = *(const float4*)(src + 4);
        float4 f2 = *(const float4*)(src + 8);
        float4 f3 = *(const float4*)(src + 12);
        *(float4*)&tile[krow][nc0]      = f0;
        *(float4*)&tile[krow][nc0 + 4]  = f1;
        *(float4*)&tile[krow][nc0 + 8]  = f2;
        *(float4*)&tile[krow][nc0 + 12] = f3;
    }
    __syncthreads();
    // write: each thread stores 2 x 16B (8 bf16 along k); per wave: 8 rows x 128 B
    #pragma unroll
    for (int rep = 0; rep < 2; ++rep) {
        const int n   = (tid >> 3) + rep * 32;  // 0..63
        const int kc0 = (tid & 7) * 8;          // 0..56
        union { uint4 v; unsigned short u[8]; } o;
        #pragma unroll
        for (int j = 0; j < 8; ++j) o.u[j] = f2bf(tile[kc0 + j][n]);
        *(uint4*)(wT + (size_t)(n0 + n) * K + k0 + kc0) = o.v;
    }
}

// ---------------- m97-style GEMM: C = A(MxK) @ Bt(NxK)^T ------------------
// A, Bt bf16 row-major. 128xTN tile, BK=64 (half the barrier drains of BK=32,
// bit-identical accumulation), global_load_lds(16B) staging with XOR-swizzled
// SOURCE chunks (rule #21: linear LDS dest + inverse-swizzled global source +
// swizzled read). LDS[r][s] = G[r][s^(r&7)], 16-B chunks; frag reads XOR the
// slot with lm&7 -> 8 lanes hit 8 distinct 16-B slots = conflict-free.
// MODE 0: fp16 out, no bias. MODE 1: fp32 out + fp32 bias.
template<int MODE, int TN>
__global__ __launch_bounds__(256) void gemm_kernel(
    const unsigned short* __restrict__ A,
    const unsigned short* __restrict__ Bt,
    void* __restrict__ Cp,
    const float* __restrict__ bias,
    int M, int N, int K)
{
    constexpr int NJ = TN / 32;          // frag cols per wave (4 or 2)
    constexpr int BRW = TN / 4;          // B rows staged per wave (32 or 16)
    __shared__ __align__(16) unsigned short As[128 * 64];
    __shared__ __align__(16) unsigned short Bs[TN * 64];
    const int tid  = threadIdx.x;
    const int wave = tid >> 6;
    const int lane = tid & 63;
    const int lm   = lane & 15;
    const int quad = lane >> 4;
    const int wm   = (wave >> 1) * 64;       // wave tile row offset
    const int wn   = (wave & 1) * (TN / 2);  // wave tile col offset
    const int bm   = blockIdx.y * 128;
    const int bn   = blockIdx.x * TN;

    f32x4 acc[4][NJ];
    const f32x4 z4 = { 0.f, 0.f, 0.f, 0.f };
    #pragma unroll
    for (int i = 0; i < 4; ++i)
        #pragma unroll
        for (int j = 0; j < NJ; ++j) acc[i][j] = z4;

    // staging map: 8 lanes/row (16 B each), 8 rows per gll16 call per wave.
    // source chunk is XOR-swizzled by row so the linear LDS dest ends up
    // holding LDS[r][s] = G[r][s^r] (s, r in 0..7).
    const int lrow = lane >> 3;                    // 0..7
    const int lcol = ((lane & 7) ^ lrow) * 8;      // swizzled source chunk
    const unsigned short* gA = A  + (size_t)(bm + wave * 32  + lrow) * K + lcol;
    const unsigned short* gB = Bt + (size_t)(bn + wave * BRW + lrow) * K + lcol;
    unsigned short* lA = &As[(wave * 32)  * 64];
    unsigned short* lB = &Bs[(wave * BRW) * 64];

    const int sx = lm & 7;                         // read-side XOR key (= row&7)
    for (int k0 = 0; k0 < K; k0 += 64) {
        __syncthreads();
        #pragma unroll
        for (int s = 0; s < 4; ++s)
            gll16(gA + k0 + (size_t)(8 * s) * K, lA + (8 * s) * 64);
        #pragma unroll
        for (int s = 0; s < BRW / 8; ++s)
            gll16(gB + k0 + (size_t)(8 * s) * K, lB + (8 * s) * 64);
        __syncthreads();
        #pragma unroll
        for (int kk = 0; kk < 2; ++kk) {
            bf16x8 af[4], bfr[NJ];
            #pragma unroll
            for (int i = 0; i < 4; ++i)
                af[i] = *(const bf16x8*)&As[(wm + i * 16 + lm) * 64
                                            + (((kk * 4 + quad) ^ sx) * 8)];
            #pragma unroll
            for (int j = 0; j < NJ; ++j)
                bfr[j] = *(const bf16x8*)&Bs[(wn + j * 16 + lm) * 64
                                             + (((kk * 4 + quad) ^ sx) * 8)];
            #pragma unroll
            for (int i = 0; i < 4; ++i)
                #pragma unroll
                for (int j = 0; j < NJ; ++j)
                    acc[i][j] = __builtin_amdgcn_mfma_f32_16x16x32_bf16(
                        af[i], bfr[j], acc[i][j], 0, 0, 0);
        }
    }

    #pragma unroll
    for (int i = 0; i < 4; ++i) {
        #pragma unroll
        for (int r = 0; r < 4; ++r) {
            const int row = bm + wm + i * 16 + quad * 4 + r;
            #pragma unroll
            for (int j = 0; j < NJ; ++j) {
                const int col = bn + wn + j * 16 + lm;
                float v = acc[i][j][r];
                if constexpr (MODE == 0) {
                    ((unsigned short*)Cp)[(size_t)row * N + col] = f2h(v);
                } else {
                    ((float*)Cp)[(size_t)row * N + col] = v + bias[col];
                }
            }
        }
    }
}

// P-fragment redistribution for PV (register-only).
// After swapped QK^T (mfma(K,Q)): lane (lm,quad) holds P[q=lm][key=16f+quad*4+rr].
// PV A-frag needs lane (lm,quad) to hold P[q=lm][key=base+quad*8+j], j=0..7.
// fa*/fb* = packed f16x2 dwords of frags FA=2kc, FB=2kc+1 (regs 01 / 23).
// Routing (verified per-case): target quad t needs frag 2kc+(t>>1) from source
// quads 2(t&1), 2(t&1)+1 -> masks: own, xor16, xor32, xor48.
__device__ __forceinline__ f16x8 pfrag(unsigned int fa0, unsigned int fa1,
                                       unsigned int fb0, unsigned int fb1,
                                       int quad) {
    const unsigned int t16_0 = (quad == 2) ? fb0 : fa0;   // q01 sends FA, q10 sends FB
    const unsigned int t16_1 = (quad == 2) ? fb1 : fa1;
    const unsigned int t32_0 = (quad == 0) ? fb0 : fa0;   // q00 sends FB, q11 sends FA
    const unsigned int t32_1 = (quad == 0) ? fb1 : fa1;
    const unsigned int t48_0 = (quad == 1) ? fb0 : fa0;   // q01 sends FB, q10 sends FA
    const unsigned int t48_1 = (quad == 1) ? fb1 : fa1;
    const unsigned int s16_0 = (unsigned int)__shfl_xor((int)t16_0, 16, 64);
    const unsigned int s16_1 = (unsigned int)__shfl_xor((int)t16_1, 16, 64);
    const unsigned int s32_0 = (unsigned int)__shfl_xor((int)t32_0, 32, 64);
    const unsigned int s32_1 = (unsigned int)__shfl_xor((int)t32_1, 32, 64);
    const unsigned int s48_0 = (unsigned int)__shfl_xor((int)t48_0, 48, 64);
    const unsigned int s48_1 = (unsigned int)__shfl_xor((int)t48_1, 48, 64);
    unsigned int w0, w1, w2, w3;
    if (quad == 0)      { w0 = fa0;   w1 = fa1;   w2 = s16_0; w3 = s16_1; }
    else if (quad == 1) { w0 = s48_0; w1 = s48_1; w2 = s32_0; w3 = s32_1; }
    else if (quad == 2) { w0 = s32_0; w1 = s32_1; w2 = s48_0; w3 = s48_1; }
    else                { w0 = s16_0; w1 = s16_1; w2 = fb0;   w3 = fb1;   }
    union { unsigned int u[4]; f16x8 v; } R;
    R.u[0] = w0; R.u[1] = w1; R.u[2] = w2; R.u[3] = w3;
    return R.v;
}

// ---------------- MFMA sparse attention (v8: 128 queries / 8 waves) -------
// Block = 512 threads = 8 waves; one (b,h), 128 queries (16 per wave).
// Grid = 32 bh * 16 chunks = 512 blocks (2/CU, 16 waves/CU).
// v8 over v6: K_global/V_global staged ONCE per 128 queries (was per 64) ->
// per-CU V^T-scatter DS work and global K/V traffic both ~halve. All compute
// paths (swapped QK^T, mask, softmax, pfrag, PV, epilogue) are byte-identical
// to the harness-verified v6; only staging sizes/strides change.
// LDS 39168 B: Kg[128][72] + Kl[144][72]; VgT[64][136] aliases Kg,
// VlT[64][152] aliases Kl, Ep(8x[16][72]) aliases VgT post-PV.
__global__ __launch_bounds__(512, 4) void attn_kernel(
    const unsigned short* __restrict__ qkv,   // fp16 (B*T) x 3072
    unsigned short* __restrict__ attn_out)    // (B*T) x D bf16
{
    __shared__ __align__(16) unsigned short smem[19584];      // 39168 B
    unsigned short* const Kg  = smem;          // [128][72]  18432 B
    unsigned short* const Kl  = smem + 9216;   // [144][72]  rows j <-> t0-15+j
    unsigned short* const VgT = smem;          // [64][136]  (aliases Kg)
    unsigned short* const VlT = smem + 9216;   // [64][152]  (aliases Kl)
    unsigned short* const Ep  = smem;          // 8 x [16][72] (aliases VgT, post-PV)

    const int tid  = threadIdx.x;
    const int wave = tid >> 6;
    const int lane = tid & 63;
    const int lm   = lane & 15;
    const int quad = lane >> 4;
    const int bx   = blockIdx.x;
    const int bh   = bx >> 4;
    const int t0   = (bx & 15) * QB;
    const int b    = bh >> 4;
    const int h    = bh & 15;

    const size_t baseQ = (size_t)(b * TT) * QKVLD + h * HD;

    // ---- stage K (global rows by threads [0,256), local rows by [256,512),
    //      local tail rows 128..143 by threads [0,32)); prefetch V to regs ----
    const int r  = (tid & 255) >> 1;   // row index within the half
    const int hf = tid & 1;            // half of the 64-dim row
    uint4 va[4];
    if (tid < 256) {
        const unsigned short* ks = qkv + baseQ + 1024 + (size_t)(16 * r) * QKVLD + hf * 32;
        const unsigned short* vs = ks + 1024;
        unsigned short* kd = Kg + r * 72 + hf * 32;
        #pragma unroll
        for (int j = 0; j < 4; ++j) *(uint4*)(kd + j * 8) = *(const uint4*)(ks + j * 8);
        #pragma unroll
        for (int j = 0; j < 4; ++j) va[j] = *(const uint4*)(vs + j * 8);
    } else {
        const int tl = t0 - 15 + r;
        unsigned short* kld = Kl + r * 72 + hf * 32;
        if (tl < 0 || tl >= TT) {           // zero pad rows: logit 0, V=0
            const uint4 z = { 0, 0, 0, 0 };
            #pragma unroll
            for (int j = 0; j < 4; ++j) { *(uint4*)(kld + j * 8) = z; va[j] = z; }
        } else {
            const unsigned short* kls = qkv + baseQ + 1024 + (size_t)tl * QKVLD + hf * 32;
            const unsigned short* vls = kls + 1024;
            #pragma unroll
            for (int j = 0; j < 4; ++j) *(uint4*)(kld + j * 8) = *(const uint4*)(kls + j * 8);
            #pragma unroll
            for (int j = 0; j < 4; ++j) va[j] = *(const uint4*)(vls + j * 8);
        }
    }
    if (tid < 32) {                          // Kl tail rows 128..143 (K only)
        const int r2 = 128 + (tid >> 1);
        const int tl = t0 - 15 + r2;
        unsigned short* kld = Kl + r2 * 72 + hf * 32;
        if (tl < 0 || tl >= TT) {
            const uint4 z = { 0, 0, 0, 0 };
            #pragma unroll
            for (int j = 0; j < 4; ++j) *(uint4*)(kld + j * 8) = z;
        } else {
            const unsigned short* kls = qkv + baseQ + 1024 + (size_t)tl * QKVLD + hf * 32;
            #pragma unroll
            for (int j = 0; j < 4; ++j) *(uint4*)(kld + j * 8) = *(const uint4*)(kls + j * 8);
        }
    }

    // ---- Q B-fragments (scaled by 1/8 = exact in fp16); q = t0+16w+lm ----
    f16x8 qf[2];
    {
        const unsigned short* qrow = qkv + baseQ + (size_t)(t0 + 16 * wave + lm) * QKVLD;
        const h2 sc = { (_Float16)0.125f, (_Float16)0.125f };
        #pragma unroll
        for (int c = 0; c < 2; ++c) {
            union { uint4 u; h2 hh[4]; f16x8 v; } U;
            U.u = *(const uint4*)(qrow + c * 32 + quad * 8);
            #pragma unroll
            for (int k = 0; k < 4; ++k) U.hh[k] *= sc;
            qf[c] = U.v;
        }
    }

    __syncthreads();   // K staged (drains V-prefetch vmcnt too)

    // ---- QK^T swapped: S[key][q].  lane (lm,quad) reg rr:
    //      q = lm, key = 16f + quad*4 + rr ----
    f32x4 sg[8], sl[2];
    const f32x4 z4 = { 0.f, 0.f, 0.f, 0.f };
    #pragma unroll
    for (int f = 0; f < 8; ++f) sg[f] = z4;
    sl[0] = z4; sl[1] = z4;
    __builtin_amdgcn_s_setprio(1);
    #pragma unroll
    for (int f = 0; f < 8; ++f)
        #pragma unroll
        for (int c = 0; c < 2; ++c)
            sg[f] = __builtin_amdgcn_mfma_f32_16x16x32_f16(
                *(const f16x8*)&Kg[(16 * f + lm) * 72 + c * 32 + quad * 8], qf[c],
                sg[f], 0, 0, 0);
    #pragma unroll
    for (int f = 0; f < 2; ++f)
        #pragma unroll
        for (int c = 0; c < 2; ++c)
            sl[f] = __builtin_amdgcn_mfma_f32_16x16x32_f16(
                *(const f16x8*)&Kl[(16 * wave + 16 * f + lm) * 72 + c * 32 + quad * 8], qf[c],
                sl[f], 0, 0, 0);
    __builtin_amdgcn_s_setprio(0);

    // ---- per-lane softmax (one q per lane); den reduce over quads ----
    float invg, invl;
    {
        float dg = 0.f, dl = 0.f;
        #pragma unroll
        for (int f = 0; f < 8; ++f)
            #pragma unroll
            for (int rr = 0; rr < 4; ++rr) {
                float e = __expf(sg[f][rr]); sg[f][rr] = e; dg += e;
            }
        #pragma unroll
        for (int f = 0; f < 2; ++f)
            #pragma unroll
            for (int rr = 0; rr < 4; ++rr) {
                const int j2 = 16 * f + quad * 4 + rr;       // local key row (wave-rel)
                const bool in = (j2 >= lm) && (j2 <= lm + 15);
                float e = in ? __expf(sl[f][rr]) : 0.f;
                sl[f][rr] = e; dl += e;
            }
        dg += __shfl_xor(dg, 16, 64);
        dg += __shfl_xor(dg, 32, 64);
        dl += __shfl_xor(dl, 16, 64);
        dl += __shfl_xor(dl, 32, 64);
        invg = 1.f / dg;
        invl = 1.f / dl;
    }

    // ---- build PV A-frags in registers (overlaps the barrier wait) ----
    f16x8 pa0, pa1, pa2, pa3, pal;
    {
        #pragma unroll
        for (int f = 0; f < 8; ++f)
            #pragma unroll
            for (int rr = 0; rr < 4; ++rr) sg[f][rr] *= invg;
        #pragma unroll
        for (int f = 0; f < 2; ++f)
            #pragma unroll
            for (int rr = 0; rr < 4; ++rr) sl[f][rr] *= invl;
        pa0 = pfrag(pk2h(sg[0][0], sg[0][1]), pk2h(sg[0][2], sg[0][3]),
                    pk2h(sg[1][0], sg[1][1]), pk2h(sg[1][2], sg[1][3]), quad);
        pa1 = pfrag(pk2h(sg[2][0], sg[2][1]), pk2h(sg[2][2], sg[2][3]),
                    pk2h(sg[3][0], sg[3][1]), pk2h(sg[3][2], sg[3][3]), quad);
        pa2 = pfrag(pk2h(sg[4][0], sg[4][1]), pk2h(sg[4][2], sg[4][3]),
                    pk2h(sg[5][0], sg[5][1]), pk2h(sg[5][2], sg[5][3]), quad);
        pa3 = pfrag(pk2h(sg[6][0], sg[6][1]), pk2h(sg[6][2], sg[6][3]),
                    pk2h(sg[7][0], sg[7][1]), pk2h(sg[7][2], sg[7][3]), quad);
        pal = pfrag(pk2h(sl[0][0], sl[0][1]), pk2h(sl[0][2], sl[0][3]),
                    pk2h(sl[1][0], sl[1][1]), pk2h(sl[1][2], sl[1][3]), quad);
    }

    __syncthreads();   // all K reads retired -> V^T may overwrite K space

    // ---- write V^T ([d][key]) from prefetch regs ----
    {
        union { uint4 u[4]; unsigned short s[32]; } U;
        #pragma unroll
        for (int j = 0; j < 4; ++j) U.u[j] = va[j];
        if (tid < 256) {
            #pragma unroll
            for (int j = 0; j < 32; ++j) VgT[(hf * 32 + j) * 136 + r] = U.s[j];
        } else {
            #pragma unroll
            for (int j = 0; j < 32; ++j) VlT[(hf * 32 + j) * 152 + r] = U.s[j];
        }
        if (tid < 32) {                      // V tail rows 128..143, JIT load
            const int r2 = 128 + (tid >> 1);
            const int tl = t0 - 15 + r2;
            union { uint4 u[4]; unsigned short s[32]; } W;
            if (tl < 0 || tl >= TT) {
                const uint4 z = { 0, 0, 0, 0 };
                #pragma unroll
                for (int j = 0; j < 4; ++j) W.u[j] = z;
            } else {
                const unsigned short* vls = qkv + baseQ + 2048 + (size_t)tl * QKVLD + hf * 32;
                #pragma unroll
                for (int j = 0; j < 4; ++j) W.u[j] = *(const uint4*)(vls + j * 8);
            }
            #pragma unroll
            for (int j = 0; j < 32; ++j) VlT[(hf * 32 + j) * 152 + r2] = W.s[j];
        }
    }

    __syncthreads();   // V^T staged

    // ---- PV: out[q][d] = sum_key P[q][key] * V[key][d] ----
    f32x4 o[4];
    #pragma unroll
    for (int c = 0; c < 4; ++c) o[c] = z4;
    __builtin_amdgcn_s_setprio(1);
    #pragma unroll
    for (int c = 0; c < 4; ++c) {
        o[c] = __builtin_amdgcn_mfma_f32_16x16x32_f16(
            pa0, *(const f16x8*)&VgT[(16 * c + lm) * 136 + 0 * 32 + quad * 8], o[c], 0, 0, 0);
        o[c] = __builtin_amdgcn_mfma_f32_16x16x32_f16(
            pa1, *(const f16x8*)&VgT[(16 * c + lm) * 136 + 1 * 32 + quad * 8], o[c], 0, 0, 0);
        o[c] = __builtin_amdgcn_mfma_f32_16x16x32_f16(
            pa2, *(const f16x8*)&VgT[(16 * c + lm) * 136 + 2 * 32 + quad * 8], o[c], 0, 0, 0);
        o[c] = __builtin_amdgcn_mfma_f32_16x16x32_f16(
            pa3, *(const f16x8*)&VgT[(16 * c + lm) * 136 + 3 * 32 + quad * 8], o[c], 0, 0, 0);
        o[c] = __builtin_amdgcn_mfma_f32_16x16x32_f16(
            pal, *(const f16x8*)&VlT[(16 * c + lm) * 152 + 16 * wave + quad * 8], o[c], 0, 0, 0);
    }
    __builtin_amdgcn_s_setprio(0);

    __syncthreads();   // all V reads retired -> epilogue may overwrite VgT

    // ---- epilogue: bf16 via per-wave LDS tile, coalesced store ----
    {
        unsigned short* const Pw = Ep + wave * (16 * 72);
        #pragma unroll
        for (int rr = 0; rr < 4; ++rr) {
            unsigned short* orow_p = Pw + (quad * 4 + rr) * 72;
            #pragma unroll
            for (int c = 0; c < 4; ++c) orow_p[16 * c + lm] = f2bf(o[c][rr]);
        }
        const int orow = lane >> 2;          // 0..15
        const int ocol = (lane & 3) * 16;    // 0,16,32,48
        const uint4 d0 = *(const uint4*)&Pw[orow * 72 + ocol];
        const uint4 d1 = *(const uint4*)&Pw[orow * 72 + ocol + 8];
        unsigned short* dst = attn_out + (size_t)(b * TT + t0 + 16 * wave + orow) * DD + h * HD + ocol;
        *(uint4*)(dst)     = d0;
        *(uint4*)(dst + 8) = d1;
    }
}

extern "C" void kernel_launch(void* const* d_in, const int* in_sizes, int n_in,
                              void* d_out, int out_size, void* d_ws, size_t ws_size,
                              hipStream_t stream) {
    const float* x      = (const float*)d_in[0];  // (B*T) x D fp32
    const float* w_qkv  = (const float*)d_in[1];  // D x 3D fp32
    const float* w_proj = (const float*)d_in[2];  // D x D fp32
    const float* b_proj = (const float*)d_in[3];  // D fp32

    // ws layout (41.94 MB total):
    //   qkv fp16 (4096x3072)      : 25.166 MB
    //   xb/attnb bf16 (4096x1024) :  8.389 MB  (aliased: xb dead after gemm1)
    //   wqkvT bf16 (3072x1024)    :  6.291 MB
    //   wprojT bf16 (1024x1024)   :  2.097 MB
    char* ws = (char*)d_ws;
    unsigned short* qkv    = (unsigned short*)ws;
    unsigned short* xb     = (unsigned short*)(ws + 25165824);
    unsigned short* attnb  = xb;
    unsigned short* wqkvT  = (unsigned short*)(ws + 25165824 + 8388608);
    unsigned short* wprojT = (unsigned short*)(ws + 25165824 + 8388608 + 6291456);
    float* out = (float*)d_out;

    // 0) fused pre-pass: x -> bf16; both weights -> transposed bf16
    prepass_kernel<<<3072, 256, 0, stream>>>(x, w_qkv, w_proj, xb, wqkvT, wprojT);

    // 1) qkv = x @ w_qkv  (bf16 MFMA, fp16 out), 128x128 tiles, 768 blocks
    gemm_kernel<0, 128><<<dim3(3072 / 128, 4096 / 128), 256, 0, stream>>>(
        xb, wqkvT, qkv, nullptr, 4096, 3072, 1024);

    // 2) sparse attention (local window + global strided), MFMA, bf16 out
    attn_kernel<<<dim3(BB * HH * (TT / QB)), 512, 0, stream>>>(qkv, attnb);

    // 3) out = attnb @ w_proj + b_proj, fp32 out — 128x128 tiles, 256 blocks
    gemm_kernel<1, 128><<<dim3(1024 / 128, 4096 / 128), 256, 0, stream>>>(
        attnb, wprojT, out, b_proj, 4096, 1024, 1024);
}

// Round 9
// 147.962 us; speedup vs baseline: 1.0624x; 1.0624x over previous
//
#include <hip/hip_runtime.h>
#include <hip/hip_bf16.h>

// Problem constants (fixed by setup_inputs)
#define BB 2
#define TT 2048
#define DD 1024
#define HH 16
#define HD 64
#define WIN 16
#define NG 128          // T / stride global tokens
#define QKVLD 3072      // 3*D row stride of qkv
#define QB 128          // attn queries per block (v8)

typedef __bf16 bf16x8 __attribute__((ext_vector_type(8)));
typedef _Float16 f16x8 __attribute__((ext_vector_type(8)));
typedef float f32x4 __attribute__((ext_vector_type(4)));
typedef _Float16 h2 __attribute__((ext_vector_type(2)));
typedef __fp16 pk2_t __attribute__((ext_vector_type(2)));   // cvt_pkrtz return type

__device__ __forceinline__ unsigned short f2bf(float f) {
    union { float f; unsigned int i; } x; x.f = f;
    unsigned int r = x.i + 0x7FFFu + ((x.i >> 16) & 1u);
    return (unsigned short)(r >> 16);
}
__device__ __forceinline__ unsigned short f2h(float f) {
    union { _Float16 h; unsigned short u; } x; x.h = (_Float16)f; return x.u;
}
// pack two f32 -> f16x2 dword (v_cvt_pkrtz_f16_f32)
__device__ __forceinline__ unsigned int pk2h(float lo, float hi) {
    union { pk2_t h; unsigned int u; } X;
    X.h = __builtin_amdgcn_cvt_pkrtz(lo, hi);
    return X.u;
}

// async global->LDS, 16 B per lane; LDS dest = wave-uniform base + lane*16
__device__ __forceinline__ void gll16(const unsigned short* g, unsigned short* l) {
    __builtin_amdgcn_global_load_lds(
        (const __attribute__((address_space(1))) void*)g,
        (__attribute__((address_space(3))) void*)l,
        16, 0, 0);
}

// ---------------- fused pre-pass (one dispatch, role per block) ----------
//   blocks [0, 2048)     : x fp32 -> xb bf16 (8 elems/thread)
//   blocks [2048, 2816)  : w_qkv (1024x3072) -> wqkvT (3072x1024) bf16, 64x64 tiles
//   blocks [2816, 3072)  : w_proj (1024x1024) -> wprojT (1024x1024) bf16, 64x64 tiles
__global__ __launch_bounds__(256) void prepass_kernel(
    const float* __restrict__ x,
    const float* __restrict__ w_qkv,
    const float* __restrict__ w_proj,
    unsigned short* __restrict__ xb,
    unsigned short* __restrict__ wqkvT,
    unsigned short* __restrict__ wprojT)
{
    __shared__ float tile[64][65];
    const int bid = blockIdx.x;
    const int tid = threadIdx.x;

    if (bid < 2048) {
        const size_t i = ((size_t)bid * 256 + tid) * 8;
        float4 f0 = *(const float4*)(x + i);
        float4 f1 = *(const float4*)(x + i + 4);
        ushort4 a = { f2bf(f0.x), f2bf(f0.y), f2bf(f0.z), f2bf(f0.w) };
        ushort4 b = { f2bf(f1.x), f2bf(f1.y), f2bf(f1.z), f2bf(f1.w) };
        *(ushort4*)(xb + i) = a;
        *(ushort4*)(xb + i + 4) = b;
        return;
    }

    const float* w;
    unsigned short* wT;
    int nblk, kblk, N;
    if (bid < 2816) {
        const int b2 = bid - 2048;
        w = w_qkv; wT = wqkvT; N = 3072;
        nblk = b2 % 48; kblk = b2 / 48;
    } else {
        const int b2 = bid - 2816;
        w = w_proj; wT = wprojT; N = 1024;
        nblk = b2 % 16; kblk = b2 / 16;
    }
    const int K = 1024;
    const int n0 = nblk * 64, k0 = kblk * 64;

    // read: 64(k) x 64(n) fp32, coalesced 16 floats per thread
    {
        const int krow = tid >> 2;             // 0..63
        const int nc0  = (tid & 3) * 16;       // 0,16,32,48
        const float* src = w + (size_t)(k0 + krow) * N + n0 + nc0;
        float4 f0 = *(const float4*)(src);
        float4 f1 = *(const float4*)(src + 4);
        float4 f2 = *(const float4*)(src + 8);
        float4 f3 = *(const float4*)(src + 12);
        *(float4*)&tile[krow][nc0]      = f0;
        *(float4*)&tile[krow][nc0 + 4]  = f1;
        *(float4*)&tile[krow][nc0 + 8]  = f2;
        *(float4*)&tile[krow][nc0 + 12] = f3;
    }
    __syncthreads();
    // write: each thread stores 2 x 16B (8 bf16 along k); per wave: 8 rows x 128 B
    #pragma unroll
    for (int rep = 0; rep < 2; ++rep) {
        const int n   = (tid >> 3) + rep * 32;  // 0..63
        const int kc0 = (tid & 7) * 8;          // 0..56
        union { uint4 v; unsigned short u[8]; } o;
        #pragma unroll
        for (int j = 0; j < 8; ++j) o.u[j] = f2bf(tile[kc0 + j][n]);
        *(uint4*)(wT + (size_t)(n0 + n) * K + k0 + kc0) = o.v;
    }
}

// ---------------- m97-style GEMM: C = A(MxK) @ Bt(NxK)^T ------------------
// A, Bt bf16 row-major. 128xTN tile, BK=64 (half the barrier drains of BK=32,
// bit-identical accumulation), global_load_lds(16B) staging with XOR-swizzled
// SOURCE chunks (rule #21: linear LDS dest + inverse-swizzled global source +
// swizzled read). LDS[r][s] = G[r][s^(r&7)], 16-B chunks; frag reads XOR the
// slot with lm&7 -> 8 lanes hit 8 distinct 16-B slots = conflict-free.
// MODE 0: fp16 out, no bias. MODE 1: fp32 out + fp32 bias.
template<int MODE, int TN>
__global__ __launch_bounds__(256) void gemm_kernel(
    const unsigned short* __restrict__ A,
    const unsigned short* __restrict__ Bt,
    void* __restrict__ Cp,
    const float* __restrict__ bias,
    int M, int N, int K)
{
    constexpr int NJ = TN / 32;          // frag cols per wave (4 or 2)
    constexpr int BRW = TN / 4;          // B rows staged per wave (32 or 16)
    __shared__ __align__(16) unsigned short As[128 * 64];
    __shared__ __align__(16) unsigned short Bs[TN * 64];
    const int tid  = threadIdx.x;
    const int wave = tid >> 6;
    const int lane = tid & 63;
    const int lm   = lane & 15;
    const int quad = lane >> 4;
    const int wm   = (wave >> 1) * 64;       // wave tile row offset
    const int wn   = (wave & 1) * (TN / 2);  // wave tile col offset
    const int bm   = blockIdx.y * 128;
    const int bn   = blockIdx.x * TN;

    f32x4 acc[4][NJ];
    const f32x4 z4 = { 0.f, 0.f, 0.f, 0.f };
    #pragma unroll
    for (int i = 0; i < 4; ++i)
        #pragma unroll
        for (int j = 0; j < NJ; ++j) acc[i][j] = z4;

    // staging map: 8 lanes/row (16 B each), 8 rows per gll16 call per wave.
    // source chunk is XOR-swizzled by row so the linear LDS dest ends up
    // holding LDS[r][s] = G[r][s^r] (s, r in 0..7).
    const int lrow = lane >> 3;                    // 0..7
    const int lcol = ((lane & 7) ^ lrow) * 8;      // swizzled source chunk
    const unsigned short* gA = A  + (size_t)(bm + wave * 32  + lrow) * K + lcol;
    const unsigned short* gB = Bt + (size_t)(bn + wave * BRW + lrow) * K + lcol;
    unsigned short* lA = &As[(wave * 32)  * 64];
    unsigned short* lB = &Bs[(wave * BRW) * 64];

    const int sx = lm & 7;                         // read-side XOR key (= row&7)
    for (int k0 = 0; k0 < K; k0 += 64) {
        __syncthreads();
        #pragma unroll
        for (int s = 0; s < 4; ++s)
            gll16(gA + k0 + (size_t)(8 * s) * K, lA + (8 * s) * 64);
        #pragma unroll
        for (int s = 0; s < BRW / 8; ++s)
            gll16(gB + k0 + (size_t)(8 * s) * K, lB + (8 * s) * 64);
        __syncthreads();
        #pragma unroll
        for (int kk = 0; kk < 2; ++kk) {
            bf16x8 af[4], bfr[NJ];
            #pragma unroll
            for (int i = 0; i < 4; ++i)
                af[i] = *(const bf16x8*)&As[(wm + i * 16 + lm) * 64
                                            + (((kk * 4 + quad) ^ sx) * 8)];
            #pragma unroll
            for (int j = 0; j < NJ; ++j)
                bfr[j] = *(const bf16x8*)&Bs[(wn + j * 16 + lm) * 64
                                             + (((kk * 4 + quad) ^ sx) * 8)];
            #pragma unroll
            for (int i = 0; i < 4; ++i)
                #pragma unroll
                for (int j = 0; j < NJ; ++j)
                    acc[i][j] = __builtin_amdgcn_mfma_f32_16x16x32_bf16(
                        af[i], bfr[j], acc[i][j], 0, 0, 0);
        }
    }

    #pragma unroll
    for (int i = 0; i < 4; ++i) {
        #pragma unroll
        for (int r = 0; r < 4; ++r) {
            const int row = bm + wm + i * 16 + quad * 4 + r;
            #pragma unroll
            for (int j = 0; j < NJ; ++j) {
                const int col = bn + wn + j * 16 + lm;
                float v = acc[i][j][r];
                if constexpr (MODE == 0) {
                    ((unsigned short*)Cp)[(size_t)row * N + col] = f2h(v);
                } else {
                    ((float*)Cp)[(size_t)row * N + col] = v + bias[col];
                }
            }
        }
    }
}

// P-fragment redistribution for PV (register-only).
// After swapped QK^T (mfma(K,Q)): lane (lm,quad) holds P[q=lm][key=16f+quad*4+rr].
// PV A-frag needs lane (lm,quad) to hold P[q=lm][key=base+quad*8+j], j=0..7.
// fa*/fb* = packed f16x2 dwords of frags FA=2kc, FB=2kc+1 (regs 01 / 23).
// Routing (verified per-case): target quad t needs frag 2kc+(t>>1) from source
// quads 2(t&1), 2(t&1)+1 -> masks: own, xor16, xor32, xor48.
__device__ __forceinline__ f16x8 pfrag(unsigned int fa0, unsigned int fa1,
                                       unsigned int fb0, unsigned int fb1,
                                       int quad) {
    const unsigned int t16_0 = (quad == 2) ? fb0 : fa0;   // q01 sends FA, q10 sends FB
    const unsigned int t16_1 = (quad == 2) ? fb1 : fa1;
    const unsigned int t32_0 = (quad == 0) ? fb0 : fa0;   // q00 sends FB, q11 sends FA
    const unsigned int t32_1 = (quad == 0) ? fb1 : fa1;
    const unsigned int t48_0 = (quad == 1) ? fb0 : fa0;   // q01 sends FB, q10 sends FA
    const unsigned int t48_1 = (quad == 1) ? fb1 : fa1;
    const unsigned int s16_0 = (unsigned int)__shfl_xor((int)t16_0, 16, 64);
    const unsigned int s16_1 = (unsigned int)__shfl_xor((int)t16_1, 16, 64);
    const unsigned int s32_0 = (unsigned int)__shfl_xor((int)t32_0, 32, 64);
    const unsigned int s32_1 = (unsigned int)__shfl_xor((int)t32_1, 32, 64);
    const unsigned int s48_0 = (unsigned int)__shfl_xor((int)t48_0, 48, 64);
    const unsigned int s48_1 = (unsigned int)__shfl_xor((int)t48_1, 48, 64);
    unsigned int w0, w1, w2, w3;
    if (quad == 0)      { w0 = fa0;   w1 = fa1;   w2 = s16_0; w3 = s16_1; }
    else if (quad == 1) { w0 = s48_0; w1 = s48_1; w2 = s32_0; w3 = s32_1; }
    else if (quad == 2) { w0 = s32_0; w1 = s32_1; w2 = s48_0; w3 = s48_1; }
    else                { w0 = s16_0; w1 = s16_1; w2 = fb0;   w3 = fb1;   }
    union { unsigned int u[4]; f16x8 v; } R;
    R.u[0] = w0; R.u[1] = w1; R.u[2] = w2; R.u[3] = w3;
    return R.v;
}

// ---------------- MFMA sparse attention (v8: 128 queries / 8 waves) -------
// Block = 512 threads = 8 waves; one (b,h), 128 queries (16 per wave).
// Grid = 32 bh * 16 chunks = 512 blocks (2/CU, 16 waves/CU).
// v8 over v6: K_global/V_global staged ONCE per 128 queries (was per 64) ->
// per-CU V^T-scatter DS work and global K/V traffic both ~halve. All compute
// paths (swapped QK^T, mask, softmax, pfrag, PV, epilogue) are byte-identical
// to the harness-verified v6; only staging sizes/strides change.
// LDS 39168 B: Kg[128][72] + Kl[144][72]; VgT[64][136] aliases Kg,
// VlT[64][152] aliases Kl, Ep(8x[16][72]) aliases VgT post-PV.
__global__ __launch_bounds__(512, 4) void attn_kernel(
    const unsigned short* __restrict__ qkv,   // fp16 (B*T) x 3072
    unsigned short* __restrict__ attn_out)    // (B*T) x D bf16
{
    __shared__ __align__(16) unsigned short smem[19584];      // 39168 B
    unsigned short* const Kg  = smem;          // [128][72]  18432 B
    unsigned short* const Kl  = smem + 9216;   // [144][72]  rows j <-> t0-15+j
    unsigned short* const VgT = smem;          // [64][136]  (aliases Kg)
    unsigned short* const VlT = smem + 9216;   // [64][152]  (aliases Kl)
    unsigned short* const Ep  = smem;          // 8 x [16][72] (aliases VgT, post-PV)

    const int tid  = threadIdx.x;
    const int wave = tid >> 6;
    const int lane = tid & 63;
    const int lm   = lane & 15;
    const int quad = lane >> 4;
    const int bx   = blockIdx.x;
    const int bh   = bx >> 4;
    const int t0   = (bx & 15) * QB;
    const int b    = bh >> 4;
    const int h    = bh & 15;

    const size_t baseQ = (size_t)(b * TT) * QKVLD + h * HD;

    // ---- stage K (global rows by threads [0,256), local rows by [256,512),
    //      local tail rows 128..143 by threads [0,32)); prefetch V to regs ----
    const int r  = (tid & 255) >> 1;   // row index within the half
    const int hf = tid & 1;            // half of the 64-dim row
    uint4 va[4];
    if (tid < 256) {
        const unsigned short* ks = qkv + baseQ + 1024 + (size_t)(16 * r) * QKVLD + hf * 32;
        const unsigned short* vs = ks + 1024;
        unsigned short* kd = Kg + r * 72 + hf * 32;
        #pragma unroll
        for (int j = 0; j < 4; ++j) *(uint4*)(kd + j * 8) = *(const uint4*)(ks + j * 8);
        #pragma unroll
        for (int j = 0; j < 4; ++j) va[j] = *(const uint4*)(vs + j * 8);
    } else {
        const int tl = t0 - 15 + r;
        unsigned short* kld = Kl + r * 72 + hf * 32;
        if (tl < 0 || tl >= TT) {           // zero pad rows: logit 0, V=0
            const uint4 z = { 0, 0, 0, 0 };
            #pragma unroll
            for (int j = 0; j < 4; ++j) { *(uint4*)(kld + j * 8) = z; va[j] = z; }
        } else {
            const unsigned short* kls = qkv + baseQ + 1024 + (size_t)tl * QKVLD + hf * 32;
            const unsigned short* vls = kls + 1024;
            #pragma unroll
            for (int j = 0; j < 4; ++j) *(uint4*)(kld + j * 8) = *(const uint4*)(kls + j * 8);
            #pragma unroll
            for (int j = 0; j < 4; ++j) va[j] = *(const uint4*)(vls + j * 8);
        }
    }
    if (tid < 32) {                          // Kl tail rows 128..143 (K only)
        const int r2 = 128 + (tid >> 1);
        const int tl = t0 - 15 + r2;
        unsigned short* kld = Kl + r2 * 72 + hf * 32;
        if (tl < 0 || tl >= TT) {
            const uint4 z = { 0, 0, 0, 0 };
            #pragma unroll
            for (int j = 0; j < 4; ++j) *(uint4*)(kld + j * 8) = z;
        } else {
            const unsigned short* kls = qkv + baseQ + 1024 + (size_t)tl * QKVLD + hf * 32;
            #pragma unroll
            for (int j = 0; j < 4; ++j) *(uint4*)(kld + j * 8) = *(const uint4*)(kls + j * 8);
        }
    }

    // ---- Q B-fragments (scaled by 1/8 = exact in fp16); q = t0+16w+lm ----
    f16x8 qf[2];
    {
        const unsigned short* qrow = qkv + baseQ + (size_t)(t0 + 16 * wave + lm) * QKVLD;
        const h2 sc = { (_Float16)0.125f, (_Float16)0.125f };
        #pragma unroll
        for (int c = 0; c < 2; ++c) {
            union { uint4 u; h2 hh[4]; f16x8 v; } U;
            U.u = *(const uint4*)(qrow + c * 32 + quad * 8);
            #pragma unroll
            for (int k = 0; k < 4; ++k) U.hh[k] *= sc;
            qf[c] = U.v;
        }
    }

    __syncthreads();   // K staged (drains V-prefetch vmcnt too)

    // ---- QK^T swapped: S[key][q].  lane (lm,quad) reg rr:
    //      q = lm, key = 16f + quad*4 + rr ----
    f32x4 sg[8], sl[2];
    const f32x4 z4 = { 0.f, 0.f, 0.f, 0.f };
    #pragma unroll
    for (int f = 0; f < 8; ++f) sg[f] = z4;
    sl[0] = z4; sl[1] = z4;
    __builtin_amdgcn_s_setprio(1);
    #pragma unroll
    for (int f = 0; f < 8; ++f)
        #pragma unroll
        for (int c = 0; c < 2; ++c)
            sg[f] = __builtin_amdgcn_mfma_f32_16x16x32_f16(
                *(const f16x8*)&Kg[(16 * f + lm) * 72 + c * 32 + quad * 8], qf[c],
                sg[f], 0, 0, 0);
    #pragma unroll
    for (int f = 0; f < 2; ++f)
        #pragma unroll
        for (int c = 0; c < 2; ++c)
            sl[f] = __builtin_amdgcn_mfma_f32_16x16x32_f16(
                *(const f16x8*)&Kl[(16 * wave + 16 * f + lm) * 72 + c * 32 + quad * 8], qf[c],
                sl[f], 0, 0, 0);
    __builtin_amdgcn_s_setprio(0);

    // ---- per-lane softmax (one q per lane); den reduce over quads ----
    float invg, invl;
    {
        float dg = 0.f, dl = 0.f;
        #pragma unroll
        for (int f = 0; f < 8; ++f)
            #pragma unroll
            for (int rr = 0; rr < 4; ++rr) {
                float e = __expf(sg[f][rr]); sg[f][rr] = e; dg += e;
            }
        #pragma unroll
        for (int f = 0; f < 2; ++f)
            #pragma unroll
            for (int rr = 0; rr < 4; ++rr) {
                const int j2 = 16 * f + quad * 4 + rr;       // local key row (wave-rel)
                const bool in = (j2 >= lm) && (j2 <= lm + 15);
                float e = in ? __expf(sl[f][rr]) : 0.f;
                sl[f][rr] = e; dl += e;
            }
        dg += __shfl_xor(dg, 16, 64);
        dg += __shfl_xor(dg, 32, 64);
        dl += __shfl_xor(dl, 16, 64);
        dl += __shfl_xor(dl, 32, 64);
        invg = 1.f / dg;
        invl = 1.f / dl;
    }

    // ---- build PV A-frags in registers (overlaps the barrier wait) ----
    f16x8 pa0, pa1, pa2, pa3, pal;
    {
        #pragma unroll
        for (int f = 0; f < 8; ++f)
            #pragma unroll
            for (int rr = 0; rr < 4; ++rr) sg[f][rr] *= invg;
        #pragma unroll
        for (int f = 0; f < 2; ++f)
            #pragma unroll
            for (int rr = 0; rr < 4; ++rr) sl[f][rr] *= invl;
        pa0 = pfrag(pk2h(sg[0][0], sg[0][1]), pk2h(sg[0][2], sg[0][3]),
                    pk2h(sg[1][0], sg[1][1]), pk2h(sg[1][2], sg[1][3]), quad);
        pa1 = pfrag(pk2h(sg[2][0], sg[2][1]), pk2h(sg[2][2], sg[2][3]),
                    pk2h(sg[3][0], sg[3][1]), pk2h(sg[3][2], sg[3][3]), quad);
        pa2 = pfrag(pk2h(sg[4][0], sg[4][1]), pk2h(sg[4][2], sg[4][3]),
                    pk2h(sg[5][0], sg[5][1]), pk2h(sg[5][2], sg[5][3]), quad);
        pa3 = pfrag(pk2h(sg[6][0], sg[6][1]), pk2h(sg[6][2], sg[6][3]),
                    pk2h(sg[7][0], sg[7][1]), pk2h(sg[7][2], sg[7][3]), quad);
        pal = pfrag(pk2h(sl[0][0], sl[0][1]), pk2h(sl[0][2], sl[0][3]),
                    pk2h(sl[1][0], sl[1][1]), pk2h(sl[1][2], sl[1][3]), quad);
    }

    __syncthreads();   // all K reads retired -> V^T may overwrite K space

    // ---- write V^T ([d][key]) from prefetch regs ----
    {
        union { uint4 u[4]; unsigned short s[32]; } U;
        #pragma unroll
        for (int j = 0; j < 4; ++j) U.u[j] = va[j];
        if (tid < 256) {
            #pragma unroll
            for (int j = 0; j < 32; ++j) VgT[(hf * 32 + j) * 136 + r] = U.s[j];
        } else {
            #pragma unroll
            for (int j = 0; j < 32; ++j) VlT[(hf * 32 + j) * 152 + r] = U.s[j];
        }
        if (tid < 32) {                      // V tail rows 128..143, JIT load
            const int r2 = 128 + (tid >> 1);
            const int tl = t0 - 15 + r2;
            union { uint4 u[4]; unsigned short s[32]; } W;
            if (tl < 0 || tl >= TT) {
                const uint4 z = { 0, 0, 0, 0 };
                #pragma unroll
                for (int j = 0; j < 4; ++j) W.u[j] = z;
            } else {
                const unsigned short* vls = qkv + baseQ + 2048 + (size_t)tl * QKVLD + hf * 32;
                #pragma unroll
                for (int j = 0; j < 4; ++j) W.u[j] = *(const uint4*)(vls + j * 8);
            }
            #pragma unroll
            for (int j = 0; j < 32; ++j) VlT[(hf * 32 + j) * 152 + r2] = W.s[j];
        }
    }

    __syncthreads();   // V^T staged

    // ---- PV: out[q][d] = sum_key P[q][key] * V[key][d] ----
    f32x4 o[4];
    #pragma unroll
    for (int c = 0; c < 4; ++c) o[c] = z4;
    __builtin_amdgcn_s_setprio(1);
    #pragma unroll
    for (int c = 0; c < 4; ++c) {
        o[c] = __builtin_amdgcn_mfma_f32_16x16x32_f16(
            pa0, *(const f16x8*)&VgT[(16 * c + lm) * 136 + 0 * 32 + quad * 8], o[c], 0, 0, 0);
        o[c] = __builtin_amdgcn_mfma_f32_16x16x32_f16(
            pa1, *(const f16x8*)&VgT[(16 * c + lm) * 136 + 1 * 32 + quad * 8], o[c], 0, 0, 0);
        o[c] = __builtin_amdgcn_mfma_f32_16x16x32_f16(
            pa2, *(const f16x8*)&VgT[(16 * c + lm) * 136 + 2 * 32 + quad * 8], o[c], 0, 0, 0);
        o[c] = __builtin_amdgcn_mfma_f32_16x16x32_f16(
            pa3, *(const f16x8*)&VgT[(16 * c + lm) * 136 + 3 * 32 + quad * 8], o[c], 0, 0, 0);
        o[c] = __builtin_amdgcn_mfma_f32_16x16x32_f16(
            pal, *(const f16x8*)&VlT[(16 * c + lm) * 152 + 16 * wave + quad * 8], o[c], 0, 0, 0);
    }
    __builtin_amdgcn_s_setprio(0);

    __syncthreads();   // all V reads retired -> epilogue may overwrite VgT

    // ---- epilogue: bf16 via per-wave LDS tile, coalesced store ----
    {
        unsigned short* const Pw = Ep + wave * (16 * 72);
        #pragma unroll
        for (int rr = 0; rr < 4; ++rr) {
            unsigned short* orow_p = Pw + (quad * 4 + rr) * 72;
            #pragma unroll
            for (int c = 0; c < 4; ++c) orow_p[16 * c + lm] = f2bf(o[c][rr]);
        }
        const int orow = lane >> 2;          // 0..15
        const int ocol = (lane & 3) * 16;    // 0,16,32,48
        const uint4 d0 = *(const uint4*)&Pw[orow * 72 + ocol];
        const uint4 d1 = *(const uint4*)&Pw[orow * 72 + ocol + 8];
        unsigned short* dst = attn_out + (size_t)(b * TT + t0 + 16 * wave + orow) * DD + h * HD + ocol;
        *(uint4*)(dst)     = d0;
        *(uint4*)(dst + 8) = d1;
    }
}

extern "C" void kernel_launch(void* const* d_in, const int* in_sizes, int n_in,
                              void* d_out, int out_size, void* d_ws, size_t ws_size,
                              hipStream_t stream) {
    const float* x      = (const float*)d_in[0];  // (B*T) x D fp32
    const float* w_qkv  = (const float*)d_in[1];  // D x 3D fp32
    const float* w_proj = (const float*)d_in[2];  // D x D fp32
    const float* b_proj = (const float*)d_in[3];  // D fp32

    // ws layout (41.94 MB total):
    //   qkv fp16 (4096x3072)      : 25.166 MB
    //   xb/attnb bf16 (4096x1024) :  8.389 MB  (aliased: xb dead after gemm1)
    //   wqkvT bf16 (3072x1024)    :  6.291 MB
    //   wprojT bf16 (1024x1024)   :  2.097 MB
    char* ws = (char*)d_ws;
    unsigned short* qkv    = (unsigned short*)ws;
    unsigned short* xb     = (unsigned short*)(ws + 25165824);
    unsigned short* attnb  = xb;
    unsigned short* wqkvT  = (unsigned short*)(ws + 25165824 + 8388608);
    unsigned short* wprojT = (unsigned short*)(ws + 25165824 + 8388608 + 6291456);
    float* out = (float*)d_out;

    // 0) fused pre-pass: x -> bf16; both weights -> transposed bf16
    prepass_kernel<<<3072, 256, 0, stream>>>(x, w_qkv, w_proj, xb, wqkvT, wprojT);

    // 1) qkv = x @ w_qkv  (bf16 MFMA, fp16 out), 128x128 tiles, 768 blocks
    gemm_kernel<0, 128><<<dim3(3072 / 128, 4096 / 128), 256, 0, stream>>>(
        xb, wqkvT, qkv, nullptr, 4096, 3072, 1024);

    // 2) sparse attention (local window + global strided), MFMA, bf16 out
    attn_kernel<<<dim3(BB * HH * (TT / QB)), 512, 0, stream>>>(qkv, attnb);

    // 3) out = attnb @ w_proj + b_proj, fp32 out — 128x64 tiles, 512 blocks
    gemm_kernel<1, 64><<<dim3(1024 / 64, 4096 / 128), 256, 0, stream>>>(
        attnb, wprojT, out, b_proj, 4096, 1024, 1024);
}